// Round 4
// baseline (1832.578 us; speedup 1.0000x reference)
//
#include <hip/hip_runtime.h>
#include <hip/hip_bf16.h>

constexpr int NLAYER = 6;
constexpr int SEQ    = 128;
constexpr int NVOCAB = 32000;

// ---------------- workspace layout (float offsets) ----------------
constexpr size_t O_H    = 0;                          // [128][256] embed output
constexpr size_t O_HN   = O_H    + (size_t)SEQ*256;   // [128][256] LN1(h) for current layer
constexpr size_t O_XZ   = O_HN   + (size_t)SEQ*256;   // [128][1024]
constexpr size_t O_U    = O_XZ   + (size_t)SEQ*1024;  // [128][512]
constexpr size_t O_XDBL = O_U    + (size_t)SEQ*512;   // [128][48] (only cols 16..47 used)
constexpr size_t O_DT   = O_XDBL + (size_t)SEQ*48;    // [128][512]
constexpr size_t O_YG   = O_DT   + (size_t)SEQ*512;   // [128][512]
constexpr size_t O_AH   = O_YG   + (size_t)SEQ*512;   // [128][256] LNf output
constexpr size_t O_BAR  = O_AH   + (size_t)SEQ*256;   // 2 uints

__device__ __forceinline__ float wsum(float p) {
    #pragma unroll
    for (int m = 1; m < 64; m <<= 1) p += __shfl_xor(p, m);
    return p;
}
__device__ __forceinline__ float dot4(float4 a, float4 b) {
    return a.x*b.x + a.y*b.y + a.z*b.z + a.w*b.w;
}

// generational grid barrier (device-scope atomics; all blocks call it the same # of times)
__device__ __forceinline__ void gbarrier(unsigned* bar, int nblk) {
    __syncthreads();
    if (threadIdx.x == 0) {
        __threadfence();
        unsigned gen = __hip_atomic_load(&bar[1], __ATOMIC_RELAXED, __HIP_MEMORY_SCOPE_AGENT);
        unsigned arr = __hip_atomic_fetch_add(&bar[0], 1u, __ATOMIC_ACQ_REL, __HIP_MEMORY_SCOPE_AGENT);
        if (arr == (unsigned)(nblk - 1)) {
            __hip_atomic_store(&bar[0], 0u, __ATOMIC_RELAXED, __HIP_MEMORY_SCOPE_AGENT);
            __hip_atomic_fetch_add(&bar[1], 1u, __ATOMIC_RELEASE, __HIP_MEMORY_SCOPE_AGENT);
        } else {
            while (__hip_atomic_load(&bar[1], __ATOMIC_ACQUIRE, __HIP_MEMORY_SCOPE_AGENT) == gen)
                __builtin_amdgcn_s_sleep(1);
        }
        __threadfence();
    }
    __syncthreads();
}

// wave-0 LayerNorm stats over a 256-float LDS row -> red[0]=mean, red[1]=rstd
__device__ __forceinline__ void ln_stats(const float* shm, float* red) {
    if (threadIdx.x < 64) {
        int lane = threadIdx.x;
        float x0 = shm[lane], x1 = shm[lane+64], x2 = shm[lane+128], x3 = shm[lane+192];
        float s = wsum(x0 + x1 + x2 + x3);
        float mean = s * (1.0f/256.0f);
        float d0 = x0-mean, d1 = x1-mean, d2 = x2-mean, d3 = x3-mean;
        float v = wsum(d0*d0 + d1*d1 + d2*d2 + d3*d3);
        if (lane == 0) { red[0] = mean; red[1] = rsqrtf(v*(1.0f/256.0f) + 1e-5f); }
    }
}

// ---------------- kernel A: zero barrier + embed + LN1 layer0 ----------------
__global__ __launch_bounds__(256) void init_kernel(
    const int* __restrict__ x, const float* __restrict__ emb,
    const float* __restrict__ n1w, const float* __restrict__ n1b,
    float* __restrict__ ws)
{
    __shared__ float sh[256];
    __shared__ float red[2];
    int r = blockIdx.x, tid = threadIdx.x;
    if (r == 0 && tid < 2) ((unsigned*)(ws + O_BAR))[tid] = 0u;
    float e = emb[(size_t)x[r]*256 + tid];
    ws[O_H + r*256 + tid] = e;
    sh[tid] = e;
    __syncthreads();
    ln_stats(sh, red);
    __syncthreads();
    ws[O_HN + r*256 + tid] = (e - red[0])*red[1]*n1w[tid] + n1b[tid];
}

// ---------------- kernel B: persistent mega-kernel (all 6 layers) ----------------
__global__ __launch_bounds__(256) void mega_kernel(
    const float* __restrict__ n1w, const float* __restrict__ n1b,
    const float* __restrict__ n2w, const float* __restrict__ n2b,
    const float* __restrict__ ipw, const float* __restrict__ cw, const float* __restrict__ cb,
    const float* __restrict__ xpw, const float* __restrict__ dpw, const float* __restrict__ dpb,
    const float* __restrict__ alog, const float* __restrict__ dsk,
    const float* __restrict__ opw, const float* __restrict__ aiw, const float* __restrict__ aib,
    const float* __restrict__ aow, const float* __restrict__ aob,
    const float* __restrict__ nfw, const float* __restrict__ nfb,
    float* __restrict__ ws)
{
    __shared__ float sX[32*256];   // 32 KB: S1 hn row-chunks / S456 v-row (first 256)
    __shared__ float sh[256];      // persistent h row for this block's sequence position
    __shared__ float su[512];      // S2 u row / S456 yg row
    __shared__ float sx[48];       // S2 xdbl row
    __shared__ float sv[256];      // S456 LN2 output
    __shared__ float red[2];
    __shared__ float s5[5*128];    // scan staging

    float* hg   = ws + O_H;
    float* hn   = ws + O_HN;
    float* xz   = ws + O_XZ;
    float* ug   = ws + O_U;
    float* xdbl = ws + O_XDBL;
    float* dtg  = ws + O_DT;
    float* yg   = ws + O_YG;
    float* AH   = ws + O_AH;
    unsigned* bar = (unsigned*)(ws + O_BAR);

    int bid  = blockIdx.x;
    int tid  = threadIdx.x;
    int lane = tid & 63;
    int wv   = tid >> 6;
    const int NB = 128;

    // load this block's persistent row
    sh[tid] = hg[bid*256 + tid];
    __syncthreads();

    for (int l = 0; l < NLAYER; ++l) {
        const float* ipw_l = ipw + (size_t)l*1024*256;
        const float* cw_l  = cw  + (size_t)l*512*4;
        const float* cb_l  = cb  + (size_t)l*512;
        const float* xpw_l = xpw + (size_t)l*48*512;
        const float* dpw_l = dpw + (size_t)l*512*16;
        const float* dpb_l = dpb + (size_t)l*512;
        const float* alog_l= alog+ (size_t)l*512*16;
        const float* dsk_l = dsk + (size_t)l*512;
        const float* opw_l = opw + (size_t)l*256*512;
        const float* aivw_l= aiw + (size_t)l*768*256 + (size_t)512*256;
        const float* aivb_l= aib + (size_t)l*768 + 512;
        const float* aow_l = aow + (size_t)l*256*256;
        const float* aob_l = aob + (size_t)l*256;
        const float* n2w_l = n2w + (size_t)l*256;
        const float* n2b_l = n2b + (size_t)l*256;

        // ---- S1: xz = hn @ ipw^T ; 2 cols per wave, hn chunk-staged in LDS ----
        {
            int c0 = (bid*4 + wv)*2;
            float4 w0 = *(const float4*)&ipw_l[(size_t)(c0+0)*256 + lane*4];
            float4 w1 = *(const float4*)&ipw_l[(size_t)(c0+1)*256 + lane*4];
            for (int ch = 0; ch < 4; ++ch) {
                int r0 = ch*32;
                __syncthreads();
                #pragma unroll
                for (int j = 0; j < 8; ++j) {
                    int off = j*1024 + tid*4;
                    *(float4*)&sX[off] = *(const float4*)&hn[r0*256 + off];
                }
                __syncthreads();
                for (int rr = 0; rr < 32; ++rr) {
                    float4 a = *(const float4*)&sX[rr*256 + lane*4];
                    float p0 = wsum(dot4(a, w0));
                    float p1 = wsum(dot4(a, w1));
                    if (lane == 0) {
                        xz[(r0+rr)*1024 + c0]     = p0;
                        xz[(r0+rr)*1024 + c0 + 1] = p1;
                    }
                }
            }
        }
        gbarrier(bar, NB);

        // ---- S2: conv+silu -> u ; x_proj -> xdbl ; dt_proj+softplus -> dt  (row = bid) ----
        {
            int t = bid;
            #pragma unroll
            for (int half = 0; half < 2; ++half) {
                int c = half*256 + tid;
                float4 cw4 = *(const float4*)&cw_l[c*4];
                float acc = cb_l[c];
                const float* cwp = (const float*)&cw4;
                #pragma unroll
                for (int k = 0; k < 4; ++k) {
                    int gt = t - 3 + k;
                    if (gt >= 0) acc += xz[gt*1024 + c] * cwp[k];
                }
                float sg = acc / (1.0f + __expf(-acc));
                su[c] = sg;
                ug[t*512 + c] = sg;
            }
            __syncthreads();
            {
                float4 a0 = *(const float4*)&su[lane*4];
                float4 a1 = *(const float4*)&su[256 + lane*4];
                for (int ci = 0; ci < 12; ++ci) {
                    int c = wv*12 + ci;
                    float4 q0 = *(const float4*)&xpw_l[(size_t)c*512 + lane*4];
                    float4 q1 = *(const float4*)&xpw_l[(size_t)c*512 + 256 + lane*4];
                    float p = wsum(dot4(a0,q0) + dot4(a1,q1));
                    if (lane == 0) {
                        sx[c] = p;
                        if (c >= 16) xdbl[t*48 + c] = p;
                    }
                }
            }
            __syncthreads();
            #pragma unroll
            for (int half = 0; half < 2; ++half) {
                int c = half*256 + tid;
                float acc = dpb_l[c];
                const float4* dp4 = (const float4*)&dpw_l[c*16];
                #pragma unroll
                for (int j4 = 0; j4 < 4; ++j4) {
                    float4 dq = dp4[j4];
                    acc += sx[j4*4+0]*dq.x + sx[j4*4+1]*dq.y
                         + sx[j4*4+2]*dq.z + sx[j4*4+3]*dq.w;
                }
                float sp = fmaxf(acc, 0.0f) + log1pf(__expf(-fabsf(acc)));
                dtg[t*512 + c] = sp;
            }
        }
        gbarrier(bar, NB);

        // ---- S3: selective scan + skip + gate -> yg (32 active blocks, 16 channels each) ----
        if (bid < 32) {
            float* sdt = s5;        float* su2 = s5 + 128;
            float* sz2 = s5 + 256;  float* sB  = s5 + 384;  float* sC = s5 + 512;
            int s  = tid & 15, dl = tid >> 4;
            int d0 = bid * 16;
            int d  = d0 + dl;
            float a_ds = -__expf(alog_l[d*16 + s]);
            float dskv = dsk_l[d];
            float hst = 0.0f;
            for (int t0 = 0; t0 < SEQ; t0 += 8) {
                __syncthreads();
                if (tid < 128) {
                    int tt = tid >> 4, j = tid & 15;
                    int t = t0 + tt;
                    sdt[tt*16+j] = dtg[t*512 + d0 + j];
                    su2[tt*16+j] = ug [t*512 + d0 + j];
                    sz2[tt*16+j] = xz [t*1024 + 512 + d0 + j];
                } else {
                    int q = tid - 128;
                    int tt = q >> 4, j = q & 15;
                    int t = t0 + tt;
                    sB[tt*16+j] = xdbl[t*48 + 16 + j];
                    sC[tt*16+j] = xdbl[t*48 + 32 + j];
                }
                __syncthreads();
                #pragma unroll
                for (int tt = 0; tt < 8; ++tt) {
                    float dtv = sdt[tt*16+dl];
                    float uv  = su2[tt*16+dl];
                    hst = __expf(dtv * a_ds) * hst + dtv * uv * sB[tt*16+s];
                    float p = hst * sC[tt*16+s];
                    p += __shfl_xor(p, 1);
                    p += __shfl_xor(p, 2);
                    p += __shfl_xor(p, 4);
                    p += __shfl_xor(p, 8);
                    if (s == 0) {
                        float zv = sz2[tt*16+dl];
                        float y = p + uv * dskv;
                        yg[(t0+tt)*512 + d] = y * (zv / (1.0f + __expf(-zv)));
                    }
                }
            }
        }
        gbarrier(bar, NB);

        // ---- S456: out_proj+resid ; LN2 ; v-proj ; attn_out+resid ; next LN (row = bid) ----
        {
            int r = bid;
            su[tid]       = yg[r*512 + tid];
            su[256 + tid] = yg[r*512 + 256 + tid];
            __syncthreads();
            {
                float4 y0 = *(const float4*)&su[lane*4];
                float4 y1 = *(const float4*)&su[256 + lane*4];
                for (int ci = 0; ci < 64; ++ci) {
                    int c = wv*64 + ci;
                    float4 q0 = *(const float4*)&opw_l[(size_t)c*512 + lane*4];
                    float4 q1 = *(const float4*)&opw_l[(size_t)c*512 + 256 + lane*4];
                    float p = wsum(dot4(y0,q0) + dot4(y1,q1));
                    if (lane == 0) sh[c] += p;
                }
            }
            __syncthreads();
            ln_stats(sh, red);
            __syncthreads();
            sv[tid] = (sh[tid] - red[0])*red[1]*n2w_l[tid] + n2b_l[tid];
            __syncthreads();
            {
                float4 a = *(const float4*)&sv[lane*4];
                for (int ci = 0; ci < 64; ++ci) {
                    int c = wv*64 + ci;
                    float4 q = *(const float4*)&aivw_l[(size_t)c*256 + lane*4];
                    float p = wsum(dot4(a, q));
                    if (lane == 0) sX[c] = p + aivb_l[c];
                }
            }
            __syncthreads();
            {
                float4 a = *(const float4*)&sX[lane*4];
                for (int ci = 0; ci < 64; ++ci) {
                    int c = wv*64 + ci;
                    float4 q = *(const float4*)&aow_l[(size_t)c*256 + lane*4];
                    float p = wsum(dot4(a, q));
                    if (lane == 0) sh[c] += p + aob_l[c];
                }
            }
            __syncthreads();
            ln_stats(sh, red);
            __syncthreads();
            if (l < NLAYER-1)
                hn[r*256 + tid] = (sh[tid] - red[0])*red[1]*n1w[(l+1)*256 + tid] + n1b[(l+1)*256 + tid];
            else
                AH[r*256 + tid] = (sh[tid] - red[0])*red[1]*nfw[tid] + nfb[tid];
        }
        gbarrier(bar, NB);
    }
}

// ---------------- kernel C: head GEMM, 128x128 tile, pad-129 LDS (2-way max) ----------------
__global__ __launch_bounds__(256) void head_kernel(
    const float* __restrict__ AH, const float* __restrict__ emb,
    const float* __restrict__ hb, float* __restrict__ out)
{
    __shared__ float sA[32*129];
    __shared__ float sW[32*129];
    int tid = threadIdx.x;
    int c0 = blockIdx.x * 128;
    int rr = tid >> 1;
    int kj = (tid & 1) * 16;
    int r4 = (tid >> 4) * 4;
    int c4 = (tid & 15) * 4;
    float acc[8][8] = {};

    for (int kc = 0; kc < 256; kc += 32) {
        __syncthreads();
        #pragma unroll
        for (int i = 0; i < 4; ++i) {
            float4 a = *(const float4*)&AH[rr*256 + kc + kj + i*4];
            sA[(kj+i*4+0)*129 + rr] = a.x;
            sA[(kj+i*4+1)*129 + rr] = a.y;
            sA[(kj+i*4+2)*129 + rr] = a.z;
            sA[(kj+i*4+3)*129 + rr] = a.w;
            float4 w = *(const float4*)&emb[(size_t)(c0+rr)*256 + kc + kj + i*4];
            sW[(kj+i*4+0)*129 + rr] = w.x;
            sW[(kj+i*4+1)*129 + rr] = w.y;
            sW[(kj+i*4+2)*129 + rr] = w.z;
            sW[(kj+i*4+3)*129 + rr] = w.w;
        }
        __syncthreads();
        #pragma unroll
        for (int k = 0; k < 32; ++k) {
            float4 a0 = *(const float4*)&sA[k*129 + r4];
            float4 a1 = *(const float4*)&sA[k*129 + 64 + r4];
            float4 b0 = *(const float4*)&sW[k*129 + c4];
            float4 b1 = *(const float4*)&sW[k*129 + 64 + c4];
            float av[8] = {a0.x,a0.y,a0.z,a0.w, a1.x,a1.y,a1.z,a1.w};
            float bv[8] = {b0.x,b0.y,b0.z,b0.w, b1.x,b1.y,b1.z,b1.w};
            #pragma unroll
            for (int i = 0; i < 8; ++i)
                #pragma unroll
                for (int j = 0; j < 8; ++j)
                    acc[i][j] += av[i]*bv[j];
        }
    }

    #pragma unroll
    for (int i = 0; i < 8; ++i) {
        int r = (i < 4) ? (r4 + i) : (64 + r4 + i - 4);
        #pragma unroll
        for (int jh = 0; jh < 2; ++jh) {
            int c = c0 + jh*64 + c4;
            float4 h4 = *(const float4*)&hb[c];
            float4 o;
            o.x = acc[i][jh*4+0] + h4.x;
            o.y = acc[i][jh*4+1] + h4.y;
            o.z = acc[i][jh*4+2] + h4.z;
            o.w = acc[i][jh*4+3] + h4.w;
            *(float4*)&out[(size_t)r*NVOCAB + c] = o;
        }
    }
}

// ---------------- launch ----------------
extern "C" void kernel_launch(void* const* d_in, const int* in_sizes, int n_in,
                              void* d_out, int out_size, void* d_ws, size_t ws_size,
                              hipStream_t stream)
{
    const int*   xin = (const int*)d_in[0];
    const float* emb = (const float*)d_in[1];
    const float* n1w = (const float*)d_in[2];
    const float* n1b = (const float*)d_in[3];
    const float* n2w = (const float*)d_in[4];
    const float* n2b = (const float*)d_in[5];
    const float* ipw = (const float*)d_in[6];
    const float* cw  = (const float*)d_in[7];
    const float* cb  = (const float*)d_in[8];
    const float* xpw = (const float*)d_in[9];
    const float* dpw = (const float*)d_in[10];
    const float* dpb = (const float*)d_in[11];
    const float* alog= (const float*)d_in[12];
    const float* dsk = (const float*)d_in[13];
    const float* opw = (const float*)d_in[14];
    const float* aiw = (const float*)d_in[15];
    const float* aib = (const float*)d_in[16];
    const float* aow = (const float*)d_in[17];
    const float* aob = (const float*)d_in[18];
    const float* nfw = (const float*)d_in[19];
    const float* nfb = (const float*)d_in[20];
    const float* hb  = (const float*)d_in[21];
    float* ws  = (float*)d_ws;
    float* out = (float*)d_out;

    init_kernel<<<SEQ, 256, 0, stream>>>(xin, emb, n1w, n1b, ws);
    mega_kernel<<<128, 256, 0, stream>>>(n1w, n1b, n2w, n2b, ipw, cw, cb, xpw, dpw, dpb,
                                         alog, dsk, opw, aiw, aib, aow, aob, nfw, nfb, ws);
    head_kernel<<<NVOCAB/128, 256, 0, stream>>>(ws + O_AH, emb, hb, out);
}